// Round 5
// baseline (283.959 us; speedup 1.0000x reference)
//
#include <hip/hip_runtime.h>

#define NROWS 8
#define NPIX  262144          // 512*512
#define K1_BPR 256            // compute: 1024 px/block, grid 2048
#define KC_BPR 128            // collect: 2048 px/block, grid 1024
#define HBINS  65536          // 16-bit histogram bins per row
#define KC_BUF 2048           // LDS candidate buffer (= px/block, always safe)
#define CAP    16384          // global candidate buffer capacity per row

// ctrl layout (dwords): [0..7]=candCount  [8..15]=rowDone  [16]=rowsResolved
#define CTRL_CC   0
#define CTRL_DONE 8
#define CTRL_FIN  16
#define CTRL_DW   32

// monotonic float->uint map (ascending float == ascending uint)
__device__ __forceinline__ unsigned int fkey(float x){
  unsigned int u = __float_as_uint(x);
  return (u & 0x80000000u) ? ~u : (u | 0x80000000u);
}

// binary softmax with a single exp
__device__ __forceinline__ void softmax2(float a0, float a1,
    float& lp0, float& lp1, float& p0, float& p1){
  float d  = a1 - a0;
  float ad = -fabsf(d);
  float e  = __expf(ad);
  float s  = 1.0f + e;
  float ls = __logf(s);
  float rs = __builtin_amdgcn_rcpf(s);
  float lpM = -ls,  lpm = ad - ls;
  float pM  = rs,   pm  = e * rs;
  bool g = (d >= 0.0f);
  lp1 = g ? lpM : lpm;  lp0 = g ? lpm : lpM;
  p1  = g ? pM  : pm;   p0  = g ? pm  : pM;
}

__device__ __forceinline__ float focal2(float tt, float lp0, float lp1,
                                        float p0, float p1){
  float q1 = 1.0f - p1, q0 = 1.0f - p0;
  return -(tt * q1 * q1 * lp1) - ((1.0f - tt) * q0 * q0 * lp0);
}

// parallel 256-bin select (256 threads): returns (bin, kRem-within-bin)
__device__ __forceinline__ uint2 selectBinV(unsigned v, unsigned kRem,
    unsigned* cum, unsigned* res){
  const int t = threadIdx.x;
  cum[t] = v;
  if (t == 0){ res[0] = 255u; res[1] = kRem; }
  __syncthreads();
  unsigned run = v;
  #pragma unroll
  for (int off = 1; off < 256; off <<= 1){
    unsigned add = (t >= off) ? cum[t - off] : 0u;
    __syncthreads();
    run += add;
    cum[t] = run;
    __syncthreads();
  }
  unsigned inc = cum[t], exc = inc - v;
  if (exc < kRem && inc >= kRem) { res[0] = (unsigned)t; res[1] = kRem - exc; }
  __syncthreads();
  uint2 r = make_uint2(res[0], res[1]);
  __syncthreads();
  return r;
}

__device__ __forceinline__ unsigned kTop(const float* frp){
  return (unsigned)((1.0 - (double)(*frp)) * (double)NPIX);   // 209715
}

// custom zero (runtime fillBuffer is slow/unpredictable for small fills)
__global__ __launch_bounds__(256) void k_zero(unsigned int* __restrict__ p, int n){
  int i = blockIdx.x * 256 + threadIdx.x;
  int stride = gridDim.x * 256;
  for (; i < n; i += stride) p[i] = 0u;
}

__global__ __launch_bounds__(256) void k_compute(
    const float* __restrict__ in1, const float* __restrict__ in2,
    const float* __restrict__ in3, const int* __restrict__ tgt,
    const float* __restrict__ kdwp,
    unsigned int* __restrict__ keys, float* __restrict__ l3out,
    unsigned int* __restrict__ hist16, unsigned int* __restrict__ partialT)
{
  __shared__ int wt[4];
  const int t = threadIdx.x;
  const int blk   = blockIdx.x;
  const int row   = blk / K1_BPR;
  const int chunk = (blk % K1_BPR) * (NPIX / K1_BPR);
  const int base  = chunk + 4 * t;
  const float kdw = *kdwp;
  const float w1  = (float)(1.0 - (double)kdw);

  const size_t ro2 = (size_t)row * 2 * NPIX;
  const size_t ro1 = (size_t)row * NPIX;

  float4 x10 = *(const float4*)(in1 + ro2 + base);
  float4 x11 = *(const float4*)(in1 + ro2 + NPIX + base);
  float4 x20 = *(const float4*)(in2 + ro2 + base);
  float4 x21 = *(const float4*)(in2 + ro2 + NPIX + base);
  float4 x30 = *(const float4*)(in3 + ro2 + base);
  float4 x31 = *(const float4*)(in3 + ro2 + NPIX + base);
  int4   tg  = *(const int4*)(tgt + ro1 + base);

  float a10[4] = {x10.x, x10.y, x10.z, x10.w};
  float a11[4] = {x11.x, x11.y, x11.z, x11.w};
  float a20[4] = {x20.x, x20.y, x20.z, x20.w};
  float a21[4] = {x21.x, x21.y, x21.z, x21.w};
  float a30[4] = {x30.x, x30.y, x30.z, x30.w};
  float a31[4] = {x31.x, x31.y, x31.z, x31.w};
  int   tgv[4] = {tg.x, tg.y, tg.z, tg.w};

  unsigned int* hrow = hist16 + (size_t)row * HBINS;
  unsigned int kv[4]; float l3v[4];
  int myT = 0;
  #pragma unroll
  for (int j = 0; j < 4; ++j){
    float tt = (float)tgv[j]; myT += tgv[j];
    float lp10, lp11, p10, p11; softmax2(a10[j], a11[j], lp10, lp11, p10, p11);
    float lp20, lp21, p20, p21; softmax2(a20[j], a21[j], lp20, lp21, p20, p21);
    float lp30, lp31, p30, p31; softmax2(a30[j], a31[j], lp30, lp31, p30, p31);
    float l1 = focal2(tt, lp10, lp11, p10, p11);
    float l2 = focal2(tt, lp20, lp21, p20, p21);
    float l3 = focal2(tt, lp30, lp31, p30, p31);
    float kdl12 = p10 * (lp10 - lp20) + p11 * (lp11 - lp21);
    float kdl21 = p20 * (lp20 - lp10) + p21 * (lp21 - lp11);
    float loss  = w1 * (l1 + l2 + l3) + kdw * (kdl12 + kdl21);
    kv[j]  = fkey(loss);
    // pack target into sign bit (focal loss >= 0): collect needn't re-read tgt
    l3v[j] = __uint_as_float(__float_as_uint(l3) | ((unsigned)tgv[j] << 31));
    // 16-bit histogram: scattered global atomics (512K addrs -> low contention)
    atomicAdd(&hrow[kv[j] >> 16], 1u);
  }
  *(uint4*)(keys + ro1 + base)   = make_uint4(kv[0], kv[1], kv[2], kv[3]);
  *(float4*)(l3out + ro1 + base) = make_float4(l3v[0], l3v[1], l3v[2], l3v[3]);

  const int lane = t & 63;
  int wsum = myT;
  #pragma unroll
  for (int o = 32; o; o >>= 1) wsum += __shfl_down(wsum, o);
  if (lane == 0) wt[t >> 6] = wsum;
  __syncthreads();
  if (t == 0) partialT[blk] = (unsigned)(wt[0] + wt[1] + wt[2] + wt[3]);
}

// one block per row: find 16-bit threshold prefix via two parallel scans
__global__ __launch_bounds__(1024) void k_scan16(
    const unsigned int* __restrict__ h16, const float* __restrict__ frp,
    unsigned int* __restrict__ selP16, unsigned int* __restrict__ selKrem)
{
  __shared__ unsigned cum[1024];
  __shared__ unsigned sres[2];
  const int t = threadIdx.x, row = blockIdx.x;
  const unsigned* hb = h16 + (size_t)row * HBINS;
  const uint4* hv = (const uint4*)(hb + t * 64);
  unsigned s = 0;
  #pragma unroll
  for (int i = 0; i < 16; ++i){ uint4 v = hv[i]; s += v.x + v.y + v.z + v.w; }
  const unsigned k0 = kTop(frp);

  // inclusive scan of 1024 chunk sums
  cum[t] = s; __syncthreads();
  unsigned run = s;
  for (int off = 1; off < 1024; off <<= 1){
    unsigned add = (t >= off) ? cum[t - off] : 0u;
    __syncthreads();
    run += add; cum[t] = run;
    __syncthreads();
  }
  unsigned inc = cum[t], exc = inc - s;
  if (exc < k0 && inc >= k0){ sres[0] = (unsigned)t; sres[1] = k0 - exc; }
  __syncthreads();
  const unsigned chunk = sres[0], rem = sres[1];
  __syncthreads();

  // scan the winning chunk's 64 bins
  unsigned bv = (t < 64) ? hb[chunk * 64 + t] : 0u;
  cum[t] = bv; __syncthreads();
  run = bv;
  for (int off = 1; off < 64; off <<= 1){
    unsigned add = (t >= off && t < 64) ? cum[t - off] : 0u;
    __syncthreads();
    if (t < 64){ run += add; cum[t] = run; }
    __syncthreads();
  }
  if (t < 64){
    unsigned inc2 = cum[t], exc2 = inc2 - bv;
    if (exc2 < rem && inc2 >= rem){
      selP16[row]  = chunk * 64 + (unsigned)t;
      selKrem[row] = rem - exc2;
    }
  }
}

// collect + (last row-block) resolve + (last row) final — 1 dispatch
__global__ __launch_bounds__(256) void k_collect(
    const unsigned int* __restrict__ keys, const float* __restrict__ l3,
    const unsigned int* __restrict__ selP16, const unsigned int* __restrict__ selKrem,
    const float* __restrict__ frp,
    unsigned int* ctrl, uint4* cand, int cap,
    float* pL3, unsigned int* pT2, const unsigned int* __restrict__ pT1,
    float* rowL3, unsigned int* rowT, float* __restrict__ out)
{
  __shared__ uint4 buf[KC_BUF];            // 32 KB staging; reused as tie buffer
  __shared__ unsigned h[256];
  __shared__ unsigned cum[256];
  __shared__ unsigned res[2];
  __shared__ unsigned cnt_s, basePos, lastFlag, finFlag, tieN;
  __shared__ float wl[4];
  __shared__ int   wt[4];
  __shared__ double dl[4];
  __shared__ unsigned long long dt_[4], dtt[4];
  const int t = threadIdx.x, lane = t & 63, wid = t >> 6;
  const int blk   = blockIdx.x;
  const int row   = blk / KC_BPR;
  const int chunk = (blk % KC_BPR) * (NPIX / KC_BPR);
  const unsigned p16 = selP16[row];
  const size_t ro = (size_t)row * NPIX;

  if (t == 0) cnt_s = 0;
  __syncthreads();

  float sL3 = 0.0f; int sT = 0;
  #pragma unroll
  for (int it = 0; it < 2; ++it){
    int base = chunk + it * 1024 + 4 * t;
    uint4  kvv = *(const uint4*)(keys + ro + base);
    float4 lv  = *(const float4*)(l3  + ro + base);
    unsigned ka[4] = {kvv.x, kvv.y, kvv.z, kvv.w};
    float    la[4] = {lv.x, lv.y, lv.z, lv.w};
    #pragma unroll
    for (int j = 0; j < 4; ++j){
      unsigned lb = __float_as_uint(la[j]);
      unsigned tv = lb >> 31;
      float    lval = __uint_as_float(lb & 0x7fffffffu);
      unsigned hi = ka[j] >> 16;
      if (hi < p16){ sL3 += lval; sT += (int)tv; }
      else if (hi == p16){
        unsigned p = atomicAdd(&cnt_s, 1u);    // LDS atomic, rare
        if (p < KC_BUF)
          buf[p] = make_uint4(ka[j], (unsigned)(base + j),
                              __float_as_uint(lval), tv);
      }
    }
  }
  #pragma unroll
  for (int o = 32; o; o >>= 1){ sL3 += __shfl_down(sL3, o); sT += __shfl_down(sT, o); }
  if (lane == 0){ wl[wid] = sL3; wt[wid] = sT; }
  __syncthreads();
  if (t == 0){
    pL3[blk] = wl[0] + wl[1] + wl[2] + wl[3];
    pT2[blk] = (unsigned)(wt[0] + wt[1] + wt[2] + wt[3]);
    basePos  = atomicAdd(&ctrl[CTRL_CC + row], cnt_s);
  }
  __syncthreads();
  unsigned n = cnt_s; if (n > KC_BUF) n = KC_BUF;
  for (unsigned i = t; i < n; i += 256){
    unsigned g = basePos + i;
    if (g < (unsigned)cap) cand[(size_t)row * cap + g] = buf[i];
  }

  // ---- signal row completion; the 128th arriver resolves the row ----
  __syncthreads();              // all stores issued (barrier drains vmcnt)
  if (t == 0){
    __threadfence();            // release: make cand/cc/partials visible
    unsigned old = atomicAdd(&ctrl[CTRL_DONE + row], 1u);
    lastFlag = (old == KC_BPR - 1) ? 1u : 0u;
  }
  __syncthreads();
  if (!lastFlag) return;
  __threadfence();              // acquire: invalidate stale cached copies

  // ---- RESOLVE row (exact 2-level select on low 16 bits + stable ties) ----
  unsigned cnt  = ctrl[CTRL_CC + row]; if (cnt > (unsigned)cap) cnt = (unsigned)cap;
  unsigned kRem = selKrem[row];        if (kRem > cnt) kRem = cnt;
  const uint4* cb = cand + (size_t)row * cap;

  h[t] = 0; __syncthreads();
  for (unsigned i = t; i < cnt; i += 256) atomicAdd(&h[(cb[i].x >> 8) & 255], 1u);
  __syncthreads();
  uint2 s2 = selectBinV(h[t], kRem, cum, res);
  const unsigned b1 = s2.x;

  h[t] = 0; __syncthreads();
  for (unsigned i = t; i < cnt; i += 256){
    unsigned key = cb[i].x;
    if (((key >> 8) & 255) == b1) atomicAdd(&h[key & 255], 1u);
  }
  __syncthreads();
  uint2 s3 = selectBinV(h[t], s2.y, cum, res);

  const unsigned T     = (p16 << 16) | (b1 << 8) | s3.x;
  const unsigned mNeed = s3.y;

  if (t == 0) tieN = 0;
  __syncthreads();
  float rL = 0.0f; int rT_ = 0;
  for (unsigned i = t; i < cnt; i += 256){
    uint4 e = cb[i];
    if (e.x < T){ rL += __uint_as_float(e.z); rT_ += (int)e.w; }
    else if (e.x == T){
      unsigned p = atomicAdd(&tieN, 1u);
      if (p < KC_BUF) buf[p] = e;       // buf reused as tie storage
    }
  }
  __syncthreads();
  unsigned tn = tieN; if (tn > KC_BUF) tn = KC_BUF;
  for (unsigned i = t; i < tn; i += 256){
    uint4 e = buf[i];
    unsigned rank = 0;
    for (unsigned j = 0; j < tn; ++j) rank += (buf[j].y < e.y) ? 1u : 0u;
    if (rank < mNeed){ rL += __uint_as_float(e.z); rT_ += (int)e.w; }
  }
  #pragma unroll
  for (int o = 32; o; o >>= 1){ rL += __shfl_down(rL, o); rT_ += __shfl_down(rT_, o); }
  if (lane == 0){ wl[wid] = rL; wt[wid] = rT_; }
  __syncthreads();
  if (t == 0){
    rowL3[row] = wl[0] + wl[1] + wl[2] + wl[3];
    rowT[row]  = (unsigned)(wt[0] + wt[1] + wt[2] + wt[3]);
    __threadfence();            // release row results
    unsigned o2 = atomicAdd(&ctrl[CTRL_FIN], 1u);
    finFlag = (o2 == NROWS - 1) ? 1u : 0u;
  }
  __syncthreads();
  if (!finFlag) return;
  __threadfence();              // acquire all rows' results + partials

  // ---- FINAL reduction ----
  unsigned long long tt = 0;
  for (int i = t; i < NROWS * K1_BPR; i += 256) tt += pT1[i];
  double sl = 0.0; unsigned long long st = 0;
  for (int i = t; i < NROWS * KC_BPR; i += 256){
    sl += (double)pL3[i]; st += pT2[i];
  }
  if (t < NROWS){ sl += (double)rowL3[t]; st += rowT[t]; }
  #pragma unroll
  for (int o = 32; o; o >>= 1){
    tt += __shfl_down(tt, o); sl += __shfl_down(sl, o); st += __shfl_down(st, o);
  }
  if (lane == 0){ dtt[wid] = tt; dl[wid] = sl; dt_[wid] = st; }
  __syncthreads();
  if (t == 0){
    tt = dtt[0] + dtt[1] + dtt[2] + dtt[3];
    sl = dl[0] + dl[1] + dl[2] + dl[3];
    st = dt_[0] + dt_[1] + dt_[2] + dt_[3];
    out[0] = (float)(sl / ((double)NROWS * (double)kTop(frp)));
    out[1] = (float)((double)st / (double)tt);
  }
}

extern "C" void kernel_launch(void* const* d_in, const int* in_sizes, int n_in,
                              void* d_out, int out_size, void* d_ws, size_t ws_size,
                              hipStream_t stream)
{
  const float* in1  = (const float*)d_in[0];
  const float* in2  = (const float*)d_in[1];
  const float* in3  = (const float*)d_in[2];
  const int*   tgt  = (const int*)d_in[3];
  const float* frp  = (const float*)d_in[4];
  const float* kdwp = (const float*)d_in[5];
  float* out = (float*)d_out;
  char*  ws  = (char*)d_ws;

  const size_t off_keys = 0;
  const size_t off_l3   = (size_t)NROWS * NPIX * 4;               // 8 MB
  const size_t off_ctrl = off_l3 + (size_t)NROWS * NPIX * 4;      // 16 MB
  const size_t off_h16  = off_ctrl + CTRL_DW * 4;                 // +128 B
  const size_t zero_end = off_h16 + (size_t)NROWS * HBINS * 4;    // +2 MB
  const size_t off_sel  = (zero_end + 255) & ~(size_t)255;        // selP16+selKrem
  const size_t off_pT1  = off_sel + 2 * NROWS * 4;
  const size_t off_pL3  = off_pT1 + (size_t)NROWS * K1_BPR * 4;
  const size_t off_pT2  = off_pL3 + (size_t)NROWS * KC_BPR * 4;
  const size_t off_rL3  = off_pT2 + (size_t)NROWS * KC_BPR * 4;
  const size_t off_rT   = off_rL3 + (size_t)NROWS * 4;
  const size_t off_cand = (off_rT + (size_t)NROWS * 4 + 255) & ~(size_t)255;

  int cap = CAP;
  if (ws_size < off_cand + (size_t)NROWS * cap * 16){
    size_t avail = (ws_size > off_cand) ? (ws_size - off_cand) / ((size_t)NROWS * 16) : 0;
    cap = (int)avail;
  }

  unsigned int* keys  = (unsigned int*)(ws + off_keys);
  float*        l3    = (float*)(ws + off_l3);
  unsigned int* ctrl  = (unsigned int*)(ws + off_ctrl);
  unsigned int* h16   = (unsigned int*)(ws + off_h16);
  unsigned int* sP16  = (unsigned int*)(ws + off_sel);
  unsigned int* sKrem = sP16 + NROWS;
  unsigned int* pT1   = (unsigned int*)(ws + off_pT1);
  float*        pL3   = (float*)(ws + off_pL3);
  unsigned int* pT2   = (unsigned int*)(ws + off_pT2);
  float*        rL3   = (float*)(ws + off_rL3);
  unsigned int* rT    = (unsigned int*)(ws + off_rT);
  uint4*        cand  = (uint4*)(ws + off_cand);

  const int nzero = (int)((zero_end - off_ctrl) / 4);   // ctrl + hist16
  k_zero<<<1024, 256, 0, stream>>>(ctrl, nzero);
  k_compute<<<NROWS * K1_BPR, 256, 0, stream>>>(in1, in2, in3, tgt, kdwp,
                                                keys, l3, h16, pT1);
  k_scan16<<<NROWS, 1024, 0, stream>>>(h16, frp, sP16, sKrem);
  k_collect<<<NROWS * KC_BPR, 256, 0, stream>>>(keys, l3, sP16, sKrem, frp,
                                                ctrl, cand, cap, pL3, pT2, pT1,
                                                rL3, rT, out);
}

// Round 6
// 113.998 us; speedup vs baseline: 2.4909x; 2.4909x over previous
//
#include <hip/hip_runtime.h>

#define NROWS  8
#define NPIX   262144         // 512*512
#define K1_BPR 256            // compute: 1024 px/block, grid 2048
#define KC_BPR 128            // collect: 2048 px/block, grid 1024
#define HB12   4096           // 12-bit histogram bins per row

// ctrl dwords: [0..7] = per-row done count (compute), [8] = collect done count
#define CTRL_ROW 0
#define CTRL_COL 8
#define CTRL_DW  32

// monotonic float->uint map (ascending float == ascending uint)
__device__ __forceinline__ unsigned int fkey(float x){
  unsigned int u = __float_as_uint(x);
  return (u & 0x80000000u) ? ~u : (u | 0x80000000u);
}

// binary softmax with a single exp
__device__ __forceinline__ void softmax2(float a0, float a1,
    float& lp0, float& lp1, float& p0, float& p1){
  float d  = a1 - a0;
  float ad = -fabsf(d);
  float e  = __expf(ad);
  float s  = 1.0f + e;
  float ls = __logf(s);
  float rs = __builtin_amdgcn_rcpf(s);
  float lpM = -ls,  lpm = ad - ls;
  float pM  = rs,   pm  = e * rs;
  bool g = (d >= 0.0f);
  lp1 = g ? lpM : lpm;  lp0 = g ? lpm : lpM;
  p1  = g ? pM  : pm;   p0  = g ? pm  : pM;
}

__device__ __forceinline__ float focal2(float tt, float lp0, float lp1,
                                        float p0, float p1){
  float q1 = 1.0f - p1, q0 = 1.0f - p0;
  return -(tt * q1 * q1 * lp1) - ((1.0f - tt) * q0 * q0 * lp0);
}

__device__ __forceinline__ unsigned kTop(const float* frp){
  return (unsigned)((1.0 - (double)(*frp)) * (double)NPIX);   // 209715
}

// custom zero (runtime fillBuffer is slow/unpredictable for small fills)
__global__ __launch_bounds__(256) void k_zero(unsigned int* __restrict__ p, int n){
  int i = blockIdx.x * 256 + threadIdx.x;
  int stride = gridDim.x * 256;
  for (; i < n; i += stride) p[i] = 0u;
}

// fused: loss compute + pack + per-block LDS hist (aggregated flush) +
// last-arriver per-row threshold scan. Packed word:
//   [31:20]=key12  [19]=target  [18:0]=l3 bits (exp8+man10, rounded)
__global__ __launch_bounds__(256) void k_compute(
    const float* __restrict__ in1, const float* __restrict__ in2,
    const float* __restrict__ in3, const int* __restrict__ tgt,
    const float* __restrict__ kdwp, const float* __restrict__ frp,
    unsigned int* __restrict__ packed, unsigned int* __restrict__ ghist,
    unsigned int* __restrict__ pT1, unsigned int* ctrl,
    unsigned int* __restrict__ selP12, unsigned int* __restrict__ selKrem,
    unsigned int* __restrict__ selCnt)
{
  __shared__ unsigned lh[HB12];        // 16 KB: 4096-bin block-local histogram
  __shared__ int wt[4];
  __shared__ unsigned lastFlag;
  const int t = threadIdx.x;
  for (int i = t; i < HB12; i += 256) lh[i] = 0;
  __syncthreads();

  const int blk   = blockIdx.x;
  const int row   = blk >> 8;                       // / K1_BPR
  const int chunk = (blk & (K1_BPR - 1)) * (NPIX / K1_BPR);
  const int base  = chunk + 4 * t;
  const float kdw = *kdwp;
  const float w1  = (float)(1.0 - (double)kdw);

  const size_t ro2 = (size_t)row * 2 * NPIX;
  const size_t ro1 = (size_t)row * NPIX;

  float4 x10 = *(const float4*)(in1 + ro2 + base);
  float4 x11 = *(const float4*)(in1 + ro2 + NPIX + base);
  float4 x20 = *(const float4*)(in2 + ro2 + base);
  float4 x21 = *(const float4*)(in2 + ro2 + NPIX + base);
  float4 x30 = *(const float4*)(in3 + ro2 + base);
  float4 x31 = *(const float4*)(in3 + ro2 + NPIX + base);
  int4   tg  = *(const int4*)(tgt + ro1 + base);

  float a10[4] = {x10.x, x10.y, x10.z, x10.w};
  float a11[4] = {x11.x, x11.y, x11.z, x11.w};
  float a20[4] = {x20.x, x20.y, x20.z, x20.w};
  float a21[4] = {x21.x, x21.y, x21.z, x21.w};
  float a30[4] = {x30.x, x30.y, x30.z, x30.w};
  float a31[4] = {x31.x, x31.y, x31.z, x31.w};
  int   tgv[4] = {tg.x, tg.y, tg.z, tg.w};

  unsigned pw[4];
  int myT = 0;
  #pragma unroll
  for (int j = 0; j < 4; ++j){
    float tt = (float)tgv[j]; myT += tgv[j];
    float lp10, lp11, p10, p11; softmax2(a10[j], a11[j], lp10, lp11, p10, p11);
    float lp20, lp21, p20, p21; softmax2(a20[j], a21[j], lp20, lp21, p20, p21);
    float lp30, lp31, p30, p31; softmax2(a30[j], a31[j], lp30, lp31, p30, p31);
    float l1 = focal2(tt, lp10, lp11, p10, p11);
    float l2 = focal2(tt, lp20, lp21, p20, p21);
    float l3 = focal2(tt, lp30, lp31, p30, p31);
    float kdl12 = p10 * (lp10 - lp20) + p11 * (lp11 - lp21);
    float kdl21 = p20 * (lp20 - lp10) + p21 * (lp21 - lp11);
    float loss  = w1 * (l1 + l2 + l3) + kdw * (kdl12 + kdl21);
    unsigned k12 = fkey(loss) >> 20;
    // l3 >= 0: keep exp8+man10, round-to-nearest via +0x1000 before shift
    unsigned lb = __float_as_uint(l3) + 0x1000u;
    pw[j] = (k12 << 20) | (((unsigned)tgv[j]) << 19) | ((lb >> 13) & 0x7FFFFu);
    atomicAdd(&lh[k12], 1u);               // LDS atomic, ~64 hot bins
  }
  *(uint4*)(packed + ro1 + base) = make_uint4(pw[0], pw[1], pw[2], pw[3]);

  const int lane = t & 63;
  int wsum = myT;
  #pragma unroll
  for (int o = 32; o; o >>= 1) wsum += __shfl_down(wsum, o);
  if (lane == 0) wt[t >> 6] = wsum;
  __syncthreads();
  if (t == 0) pT1[blk] = (unsigned)(wt[0] + wt[1] + wt[2] + wt[3]);

  // flush block-local hist -> global (aggregated: few hundred atomics/block)
  unsigned int* gh = ghist + (size_t)row * HB12;
  for (int i = t; i < HB12; i += 256){
    unsigned v = lh[i];
    if (v) atomicAdd(&gh[i], v);
  }
  __syncthreads();
  if (t == 0){
    __threadfence();                       // release hist/packed/pT1
    unsigned old = atomicAdd(&ctrl[CTRL_ROW + row], 1u);
    lastFlag = (old == K1_BPR - 1) ? 1u : 0u;
  }
  __syncthreads();
  if (!lastFlag) return;
  __threadfence();                         // acquire other blocks' hist

  // ---- last block of the row: find 12-bit threshold bin ----
  const uint4* gv = (const uint4*)(gh + t * 16);
  uint4 q0 = gv[0], q1 = gv[1], q2 = gv[2], q3 = gv[3];
  unsigned b[16] = {q0.x,q0.y,q0.z,q0.w, q1.x,q1.y,q1.z,q1.w,
                    q2.x,q2.y,q2.z,q2.w, q3.x,q3.y,q3.z,q3.w};
  unsigned s = 0;
  #pragma unroll
  for (int i = 0; i < 16; ++i) s += b[i];

  lh[t] = s; __syncthreads();
  unsigned run = s;
  #pragma unroll
  for (int off = 1; off < 256; off <<= 1){
    unsigned add = (t >= off) ? lh[t - off] : 0u;
    __syncthreads();
    run += add; lh[t] = run;
    __syncthreads();
  }
  const unsigned k0 = kTop(frp);
  unsigned inc = run, exc = run - s;
  if (exc < k0 && inc >= k0){              // exactly one thread
    unsigned rem = k0 - exc;
    #pragma unroll
    for (int i = 0; i < 16; ++i){
      unsigned c = b[i];
      if (rem <= c){
        selP12[row]  = (unsigned)(t * 16 + i);
        selKrem[row] = rem;
        selCnt[row]  = c;
        break;
      }
      rem -= c;
    }
  }
}

// collect (below/tie sums) + last-arriver final reduction -> out
__global__ __launch_bounds__(256) void k_collect(
    const unsigned int* __restrict__ packed,
    const unsigned int* __restrict__ selP12,
    const unsigned int* __restrict__ selKrem,
    const unsigned int* __restrict__ selCnt,
    const float* __restrict__ frp, const unsigned int* __restrict__ pT1,
    float* __restrict__ pB3, unsigned int* __restrict__ pBT,
    float* __restrict__ pT3, unsigned int* __restrict__ pTT,
    unsigned int* ctrl, float* __restrict__ out)
{
  __shared__ float wf[8];
  __shared__ int   wi[8];
  __shared__ double dd[12];
  __shared__ unsigned lastFlag;
  const int t = threadIdx.x, lane = t & 63, wid = t >> 6;
  const int blk   = blockIdx.x;
  const int row   = blk >> 7;                       // / KC_BPR
  const int chunk = (blk & (KC_BPR - 1)) * (NPIX / KC_BPR);
  const unsigned T = selP12[row];
  const size_t ro = (size_t)row * NPIX;

  float b3 = 0.0f, t3 = 0.0f; int bt = 0, tt2 = 0;
  #pragma unroll
  for (int it = 0; it < 2; ++it){
    int base = chunk + it * 1024 + 4 * t;
    uint4 w = *(const uint4*)(packed + ro + base);
    unsigned a[4] = {w.x, w.y, w.z, w.w};
    #pragma unroll
    for (int j = 0; j < 4; ++j){
      unsigned k12 = a[j] >> 20;
      float l3 = __uint_as_float((a[j] & 0x7FFFFu) << 13);
      int   tv = (int)((a[j] >> 19) & 1u);
      if (k12 < T){ b3 += l3; bt += tv; }
      else if (k12 == T){ t3 += l3; tt2 += tv; }
    }
  }
  #pragma unroll
  for (int o = 32; o; o >>= 1){
    b3 += __shfl_down(b3, o); t3 += __shfl_down(t3, o);
    bt += __shfl_down(bt, o); tt2 += __shfl_down(tt2, o);
  }
  if (lane == 0){ wf[wid] = b3; wf[4 + wid] = t3; wi[wid] = bt; wi[4 + wid] = tt2; }
  __syncthreads();
  if (t == 0){
    pB3[blk] = wf[0] + wf[1] + wf[2] + wf[3];
    pT3[blk] = wf[4] + wf[5] + wf[6] + wf[7];
    pBT[blk] = (unsigned)(wi[0] + wi[1] + wi[2] + wi[3]);
    pTT[blk] = (unsigned)(wi[4] + wi[5] + wi[6] + wi[7]);
    __threadfence();                       // release partials
    unsigned old = atomicAdd(&ctrl[CTRL_COL], 1u);
    lastFlag = (old == NROWS * KC_BPR - 1) ? 1u : 0u;
  }
  __syncthreads();
  if (!lastFlag) return;
  __threadfence();                         // acquire all partials

  // ---- final: per-row frac-weighted combine + total-target sum ----
  const int r = t >> 5;                    // 4 blocks/thread, all in row r
  const double frac = (double)selKrem[r] / (double)selCnt[r];
  double n0 = 0.0, n1 = 0.0, tt = 0.0;
  #pragma unroll
  for (int m = 0; m < 4; ++m){
    int bI = t * 4 + m;
    n0 += (double)pB3[bI] + frac * (double)pT3[bI];
    n1 += (double)pBT[bI] + frac * (double)pTT[bI];
  }
  #pragma unroll
  for (int i = 0; i < 8; ++i) tt += (double)pT1[t * 8 + i];
  #pragma unroll
  for (int o = 32; o; o >>= 1){
    n0 += __shfl_down(n0, o); n1 += __shfl_down(n1, o); tt += __shfl_down(tt, o);
  }
  if (lane == 0){ dd[wid] = n0; dd[4 + wid] = n1; dd[8 + wid] = tt; }
  __syncthreads();
  if (t == 0){
    double s0 = dd[0] + dd[1] + dd[2] + dd[3];
    double s1 = dd[4] + dd[5] + dd[6] + dd[7];
    double st = dd[8] + dd[9] + dd[10] + dd[11];
    out[0] = (float)(s0 / ((double)NROWS * (double)kTop(frp)));
    out[1] = (float)(s1 / st);
  }
}

extern "C" void kernel_launch(void* const* d_in, const int* in_sizes, int n_in,
                              void* d_out, int out_size, void* d_ws, size_t ws_size,
                              hipStream_t stream)
{
  const float* in1  = (const float*)d_in[0];
  const float* in2  = (const float*)d_in[1];
  const float* in3  = (const float*)d_in[2];
  const int*   tgt  = (const int*)d_in[3];
  const float* frp  = (const float*)d_in[4];
  const float* kdwp = (const float*)d_in[5];
  float* out = (float*)d_out;
  char*  ws  = (char*)d_ws;

  const size_t off_packed = 0;                                    // 8 MB
  const size_t off_ctrl   = (size_t)NROWS * NPIX * 4;
  const size_t off_ghist  = off_ctrl + CTRL_DW * 4;               // 128 KB
  const size_t zero_end   = off_ghist + (size_t)NROWS * HB12 * 4;
  const size_t off_sel    = (zero_end + 255) & ~(size_t)255;      // 3*NROWS u32
  const size_t off_pT1    = off_sel + 3 * NROWS * 4;              // 2048 u32
  const size_t off_pB3    = off_pT1 + (size_t)NROWS * K1_BPR * 4;
  const size_t off_pBT    = off_pB3 + (size_t)NROWS * KC_BPR * 4;
  const size_t off_pT3    = off_pBT + (size_t)NROWS * KC_BPR * 4;
  const size_t off_pTT    = off_pT3 + (size_t)NROWS * KC_BPR * 4;

  unsigned int* packed = (unsigned int*)(ws + off_packed);
  unsigned int* ctrl   = (unsigned int*)(ws + off_ctrl);
  unsigned int* ghist  = (unsigned int*)(ws + off_ghist);
  unsigned int* sP12   = (unsigned int*)(ws + off_sel);
  unsigned int* sKrem  = sP12 + NROWS;
  unsigned int* sCnt   = sP12 + 2 * NROWS;
  unsigned int* pT1    = (unsigned int*)(ws + off_pT1);
  float*        pB3    = (float*)(ws + off_pB3);
  unsigned int* pBT    = (unsigned int*)(ws + off_pBT);
  float*        pT3    = (float*)(ws + off_pT3);
  unsigned int* pTT    = (unsigned int*)(ws + off_pTT);

  const int nzero = (int)((zero_end - off_ctrl) / 4);   // ctrl + ghist
  k_zero<<<64, 256, 0, stream>>>(ctrl, nzero);
  k_compute<<<NROWS * K1_BPR, 256, 0, stream>>>(in1, in2, in3, tgt, kdwp, frp,
                                                packed, ghist, pT1, ctrl,
                                                sP12, sKrem, sCnt);
  k_collect<<<NROWS * KC_BPR, 256, 0, stream>>>(packed, sP12, sKrem, sCnt,
                                                frp, pT1, pB3, pBT, pT3, pTT,
                                                ctrl, out);
}

// Round 7
// 95.467 us; speedup vs baseline: 2.9744x; 1.1941x over previous
//
#include <hip/hip_runtime.h>

#define NROWS  8
#define NPIX   262144         // 512*512
#define K1_BPR 256            // compute: 1024 px/block, grid 2048
#define KC_BPR 128            // collect: 2048 px/block, grid 1024
#define HB12   4096           // 12-bit histogram bins per row

// ctrl dwords: [0..7] = per-row done count (compute), [8] = collect done count
#define CTRL_ROW 0
#define CTRL_COL 8
#define CTRL_DW  32

// monotonic float->uint map (ascending float == ascending uint)
__device__ __forceinline__ unsigned int fkey(float x){
  unsigned int u = __float_as_uint(x);
  return (u & 0x80000000u) ? ~u : (u | 0x80000000u);
}

// binary softmax with a single exp
__device__ __forceinline__ void softmax2(float a0, float a1,
    float& lp0, float& lp1, float& p0, float& p1){
  float d  = a1 - a0;
  float ad = -fabsf(d);
  float e  = __expf(ad);
  float s  = 1.0f + e;
  float ls = __logf(s);
  float rs = __builtin_amdgcn_rcpf(s);
  float lpM = -ls,  lpm = ad - ls;
  float pM  = rs,   pm  = e * rs;
  bool g = (d >= 0.0f);
  lp1 = g ? lpM : lpm;  lp0 = g ? lpm : lpM;
  p1  = g ? pM  : pm;   p0  = g ? pm  : pM;
}

__device__ __forceinline__ float focal2(float tt, float lp0, float lp1,
                                        float p0, float p1){
  float q1 = 1.0f - p1, q0 = 1.0f - p0;
  return -(tt * q1 * q1 * lp1) - ((1.0f - tt) * q0 * q0 * lp0);
}

__device__ __forceinline__ unsigned kTop(const float* frp){
  return (unsigned)((1.0 - (double)(*frp)) * (double)NPIX);   // 209715
}

// custom zero (runtime fillBuffer is slow/unpredictable for small fills)
__global__ __launch_bounds__(256) void k_zero(unsigned int* __restrict__ p, int n){
  int i = blockIdx.x * 256 + threadIdx.x;
  int stride = gridDim.x * 256;
  for (; i < n; i += stride) p[i] = 0u;
}

// fused: loss compute + pack + per-block LDS hist (wave-ballot aggregated;
// raw per-pixel LDS atomics serialized same-address: 183K bank-conflict
// cycles, 106us in round 6) + last-arriver per-row threshold scan.
// Packed word: [31:20]=key12  [19]=target  [18:0]=l3 bits (exp8+man10, rnd)
__global__ __launch_bounds__(256) void k_compute(
    const float* __restrict__ in1, const float* __restrict__ in2,
    const float* __restrict__ in3, const int* __restrict__ tgt,
    const float* __restrict__ kdwp, const float* __restrict__ frp,
    unsigned int* __restrict__ packed, unsigned int* __restrict__ ghist,
    unsigned int* __restrict__ pT1, unsigned int* ctrl,
    unsigned int* __restrict__ selP12, unsigned int* __restrict__ selKrem,
    unsigned int* __restrict__ selCnt)
{
  __shared__ unsigned lh[HB12];        // 16 KB: 4096-bin block-local histogram
  __shared__ int wt[4];
  __shared__ unsigned lastFlag;
  const int t = threadIdx.x;
  for (int i = t; i < HB12; i += 256) lh[i] = 0;
  __syncthreads();

  const int blk   = blockIdx.x;
  const int row   = blk >> 8;                       // / K1_BPR
  const int chunk = (blk & (K1_BPR - 1)) * (NPIX / K1_BPR);
  const int base  = chunk + 4 * t;
  const float kdw = *kdwp;
  const float w1  = (float)(1.0 - (double)kdw);

  const size_t ro2 = (size_t)row * 2 * NPIX;
  const size_t ro1 = (size_t)row * NPIX;

  float4 x10 = *(const float4*)(in1 + ro2 + base);
  float4 x11 = *(const float4*)(in1 + ro2 + NPIX + base);
  float4 x20 = *(const float4*)(in2 + ro2 + base);
  float4 x21 = *(const float4*)(in2 + ro2 + NPIX + base);
  float4 x30 = *(const float4*)(in3 + ro2 + base);
  float4 x31 = *(const float4*)(in3 + ro2 + NPIX + base);
  int4   tg  = *(const int4*)(tgt + ro1 + base);

  float a10[4] = {x10.x, x10.y, x10.z, x10.w};
  float a11[4] = {x11.x, x11.y, x11.z, x11.w};
  float a20[4] = {x20.x, x20.y, x20.z, x20.w};
  float a21[4] = {x21.x, x21.y, x21.z, x21.w};
  float a30[4] = {x30.x, x30.y, x30.z, x30.w};
  float a31[4] = {x31.x, x31.y, x31.z, x31.w};
  int   tgv[4] = {tg.x, tg.y, tg.z, tg.w};

  unsigned pw[4]; unsigned kb[4];
  int myT = 0;
  #pragma unroll
  for (int j = 0; j < 4; ++j){
    float tt = (float)tgv[j]; myT += tgv[j];
    float lp10, lp11, p10, p11; softmax2(a10[j], a11[j], lp10, lp11, p10, p11);
    float lp20, lp21, p20, p21; softmax2(a20[j], a21[j], lp20, lp21, p20, p21);
    float lp30, lp31, p30, p31; softmax2(a30[j], a31[j], lp30, lp31, p30, p31);
    float l1 = focal2(tt, lp10, lp11, p10, p11);
    float l2 = focal2(tt, lp20, lp21, p20, p21);
    float l3 = focal2(tt, lp30, lp31, p30, p31);
    float kdl12 = p10 * (lp10 - lp20) + p11 * (lp11 - lp21);
    float kdl21 = p20 * (lp20 - lp10) + p21 * (lp21 - lp11);
    float loss  = w1 * (l1 + l2 + l3) + kdw * (kdl12 + kdl21);
    unsigned k12 = fkey(loss) >> 20;
    kb[j] = k12;
    // l3 >= 0: keep exp8+man10, round-to-nearest via +0x1000 before shift
    unsigned lb = __float_as_uint(l3) + 0x1000u;
    pw[j] = (k12 << 20) | (((unsigned)tgv[j]) << 19) | ((lb >> 13) & 0x7FFFFu);
  }
  *(uint4*)(packed + ro1 + base) = make_uint4(pw[0], pw[1], pw[2], pw[3]);

  // wave-ballot aggregated histogram: ONE LDS atomic per distinct bin/wave
  const int lane = t & 63;
  #pragma unroll
  for (int j = 0; j < 4; ++j){
    unsigned bin = kb[j];
    unsigned long long rem = ~0ull;
    while (rem){
      int lead = __ffsll(rem) - 1;
      unsigned leadBin = (unsigned)__shfl((int)bin, lead);
      unsigned long long same = __ballot(bin == leadBin);
      if (lane == lead) atomicAdd(&lh[leadBin], (unsigned)__popcll(same));
      rem &= ~same;
    }
  }

  int wsum = myT;
  #pragma unroll
  for (int o = 32; o; o >>= 1) wsum += __shfl_down(wsum, o);
  if (lane == 0) wt[t >> 6] = wsum;
  __syncthreads();
  if (t == 0) pT1[blk] = (unsigned)(wt[0] + wt[1] + wt[2] + wt[3]);

  // flush block-local hist -> global (aggregated: few hundred atomics/block)
  unsigned int* gh = ghist + (size_t)row * HB12;
  for (int i = t; i < HB12; i += 256){
    unsigned v = lh[i];
    if (v) atomicAdd(&gh[i], v);
  }
  __syncthreads();
  if (t == 0){
    __threadfence();                       // release hist/packed/pT1
    unsigned old = atomicAdd(&ctrl[CTRL_ROW + row], 1u);
    lastFlag = (old == K1_BPR - 1) ? 1u : 0u;
  }
  __syncthreads();
  if (!lastFlag) return;
  __threadfence();                         // acquire other blocks' hist

  // ---- last block of the row: find 12-bit threshold bin ----
  const uint4* gv = (const uint4*)(gh + t * 16);
  uint4 q0 = gv[0], q1 = gv[1], q2 = gv[2], q3 = gv[3];
  unsigned b[16] = {q0.x,q0.y,q0.z,q0.w, q1.x,q1.y,q1.z,q1.w,
                    q2.x,q2.y,q2.z,q2.w, q3.x,q3.y,q3.z,q3.w};
  unsigned s = 0;
  #pragma unroll
  for (int i = 0; i < 16; ++i) s += b[i];

  lh[t] = s; __syncthreads();
  unsigned run = s;
  #pragma unroll
  for (int off = 1; off < 256; off <<= 1){
    unsigned add = (t >= off) ? lh[t - off] : 0u;
    __syncthreads();
    run += add; lh[t] = run;
    __syncthreads();
  }
  const unsigned k0 = kTop(frp);
  unsigned inc = run, exc = run - s;
  if (exc < k0 && inc >= k0){              // exactly one thread
    unsigned rem = k0 - exc;
    #pragma unroll
    for (int i = 0; i < 16; ++i){
      unsigned c = b[i];
      if (rem <= c){
        selP12[row]  = (unsigned)(t * 16 + i);
        selKrem[row] = rem;
        selCnt[row]  = c;
        break;
      }
      rem -= c;
    }
  }
}

// collect (below/tie sums) + last-arriver final reduction -> out
__global__ __launch_bounds__(256) void k_collect(
    const unsigned int* __restrict__ packed,
    const unsigned int* __restrict__ selP12,
    const unsigned int* __restrict__ selKrem,
    const unsigned int* __restrict__ selCnt,
    const float* __restrict__ frp, const unsigned int* __restrict__ pT1,
    float* __restrict__ pB3, unsigned int* __restrict__ pBT,
    float* __restrict__ pT3, unsigned int* __restrict__ pTT,
    unsigned int* ctrl, float* __restrict__ out)
{
  __shared__ float wf[8];
  __shared__ int   wi[8];
  __shared__ double dd[12];
  __shared__ unsigned lastFlag;
  const int t = threadIdx.x, lane = t & 63, wid = t >> 6;
  const int blk   = blockIdx.x;
  const int row   = blk >> 7;                       // / KC_BPR
  const int chunk = (blk & (KC_BPR - 1)) * (NPIX / KC_BPR);
  const unsigned T = selP12[row];
  const size_t ro = (size_t)row * NPIX;

  float b3 = 0.0f, t3 = 0.0f; int bt = 0, tt2 = 0;
  #pragma unroll
  for (int it = 0; it < 2; ++it){
    int base = chunk + it * 1024 + 4 * t;
    uint4 w = *(const uint4*)(packed + ro + base);
    unsigned a[4] = {w.x, w.y, w.z, w.w};
    #pragma unroll
    for (int j = 0; j < 4; ++j){
      unsigned k12 = a[j] >> 20;
      float l3 = __uint_as_float((a[j] & 0x7FFFFu) << 13);
      int   tv = (int)((a[j] >> 19) & 1u);
      if (k12 < T){ b3 += l3; bt += tv; }
      else if (k12 == T){ t3 += l3; tt2 += tv; }
    }
  }
  #pragma unroll
  for (int o = 32; o; o >>= 1){
    b3 += __shfl_down(b3, o); t3 += __shfl_down(t3, o);
    bt += __shfl_down(bt, o); tt2 += __shfl_down(tt2, o);
  }
  if (lane == 0){ wf[wid] = b3; wf[4 + wid] = t3; wi[wid] = bt; wi[4 + wid] = tt2; }
  __syncthreads();
  if (t == 0){
    pB3[blk] = wf[0] + wf[1] + wf[2] + wf[3];
    pT3[blk] = wf[4] + wf[5] + wf[6] + wf[7];
    pBT[blk] = (unsigned)(wi[0] + wi[1] + wi[2] + wi[3]);
    pTT[blk] = (unsigned)(wi[4] + wi[5] + wi[6] + wi[7]);
    __threadfence();                       // release partials
    unsigned old = atomicAdd(&ctrl[CTRL_COL], 1u);
    lastFlag = (old == NROWS * KC_BPR - 1) ? 1u : 0u;
  }
  __syncthreads();
  if (!lastFlag) return;
  __threadfence();                         // acquire all partials

  // ---- final: per-row frac-weighted combine + total-target sum ----
  const int r = t >> 5;                    // 4 blocks/thread, all in row r
  const double frac = (double)selKrem[r] / (double)selCnt[r];
  double n0 = 0.0, n1 = 0.0, tt = 0.0;
  #pragma unroll
  for (int m = 0; m < 4; ++m){
    int bI = t * 4 + m;
    n0 += (double)pB3[bI] + frac * (double)pT3[bI];
    n1 += (double)pBT[bI] + frac * (double)pTT[bI];
  }
  #pragma unroll
  for (int i = 0; i < 8; ++i) tt += (double)pT1[t * 8 + i];
  #pragma unroll
  for (int o = 32; o; o >>= 1){
    n0 += __shfl_down(n0, o); n1 += __shfl_down(n1, o); tt += __shfl_down(tt, o);
  }
  if (lane == 0){ dd[wid] = n0; dd[4 + wid] = n1; dd[8 + wid] = tt; }
  __syncthreads();
  if (t == 0){
    double s0 = dd[0] + dd[1] + dd[2] + dd[3];
    double s1 = dd[4] + dd[5] + dd[6] + dd[7];
    double st = dd[8] + dd[9] + dd[10] + dd[11];
    out[0] = (float)(s0 / ((double)NROWS * (double)kTop(frp)));
    out[1] = (float)(s1 / st);
  }
}

extern "C" void kernel_launch(void* const* d_in, const int* in_sizes, int n_in,
                              void* d_out, int out_size, void* d_ws, size_t ws_size,
                              hipStream_t stream)
{
  const float* in1  = (const float*)d_in[0];
  const float* in2  = (const float*)d_in[1];
  const float* in3  = (const float*)d_in[2];
  const int*   tgt  = (const int*)d_in[3];
  const float* frp  = (const float*)d_in[4];
  const float* kdwp = (const float*)d_in[5];
  float* out = (float*)d_out;
  char*  ws  = (char*)d_ws;

  const size_t off_packed = 0;                                    // 8 MB
  const size_t off_ctrl   = (size_t)NROWS * NPIX * 4;
  const size_t off_ghist  = off_ctrl + CTRL_DW * 4;               // 128 KB
  const size_t zero_end   = off_ghist + (size_t)NROWS * HB12 * 4;
  const size_t off_sel    = (zero_end + 255) & ~(size_t)255;      // 3*NROWS u32
  const size_t off_pT1    = off_sel + 3 * NROWS * 4;              // 2048 u32
  const size_t off_pB3    = off_pT1 + (size_t)NROWS * K1_BPR * 4;
  const size_t off_pBT    = off_pB3 + (size_t)NROWS * KC_BPR * 4;
  const size_t off_pT3    = off_pBT + (size_t)NROWS * KC_BPR * 4;
  const size_t off_pTT    = off_pT3 + (size_t)NROWS * KC_BPR * 4;

  unsigned int* packed = (unsigned int*)(ws + off_packed);
  unsigned int* ctrl   = (unsigned int*)(ws + off_ctrl);
  unsigned int* ghist  = (unsigned int*)(ws + off_ghist);
  unsigned int* sP12   = (unsigned int*)(ws + off_sel);
  unsigned int* sKrem  = sP12 + NROWS;
  unsigned int* sCnt   = sP12 + 2 * NROWS;
  unsigned int* pT1    = (unsigned int*)(ws + off_pT1);
  float*        pB3    = (float*)(ws + off_pB3);
  unsigned int* pBT    = (unsigned int*)(ws + off_pBT);
  float*        pT3    = (float*)(ws + off_pT3);
  unsigned int* pTT    = (unsigned int*)(ws + off_pTT);

  const int nzero = (int)((zero_end - off_ctrl) / 4);   // ctrl + ghist
  k_zero<<<64, 256, 0, stream>>>(ctrl, nzero);
  k_compute<<<NROWS * K1_BPR, 256, 0, stream>>>(in1, in2, in3, tgt, kdwp, frp,
                                                packed, ghist, pT1, ctrl,
                                                sP12, sKrem, sCnt);
  k_collect<<<NROWS * KC_BPR, 256, 0, stream>>>(packed, sP12, sKrem, sCnt,
                                                frp, pT1, pB3, pBT, pT3, pTT,
                                                ctrl, out);
}